// Round 6
// baseline (7485.194 us; speedup 1.0000x reference)
//
#include <hip/hip_runtime.h>

#define IMG 512
#define HWROW 512
#define NPATCH 1024
#define GRIDSZ 32
#define CLAT 128
#define OUTC 64
#define MiB (1048576UL)

static inline int imax(int a, int b) { return a > b ? a : b; }
static inline int imin(int a, int b) { return a < b ? a : b; }

// Composite 1D weight (corner-0 weight) for 2 -> 16 via three x2 bilinear
// (half-pixel centers, edge-clamped) upsamples. a[i] + a[15-i] == 1.
__device__ const float A16[16] = {
    1.0f, 0.984375f, 0.953125f, 0.90625f, 0.84375f, 0.765625f, 0.671875f,
    0.5625f, 0.4375f, 0.328125f, 0.234375f, 0.15625f, 0.09375f, 0.046875f,
    0.015625f, 0.0f};

// ---------------------------------------------------------------------------
// Kernel 0: zero the Q/Bias/Cnt accumulators (d_ws is poisoned 0xAA each call).
// ---------------------------------------------------------------------------
__global__ __launch_bounds__(256) void zero_kernel(float* __restrict__ p, int n)
{
    int i = blockIdx.x * 256 + threadIdx.x;
    if (i < n) p[i] = 0.0f;
}

// ---------------------------------------------------------------------------
// Kernel 1: per-patch projection of the 4 latent corners through the expert's
// 1x1 conv weight, accumulated per tile. Positions are tile-aligned, so the
// overlap-add scatter reduces to per-tile sums; bilinear is linear so corners
// can be summed before expanding.
// ---------------------------------------------------------------------------
__global__ __launch_bounds__(256) void patch_project(
    const float* __restrict__ latents,   // [N][128][2][2]
    const int* __restrict__ expert_ids,  // [N]
    const int* __restrict__ positions,   // [N][2]  (x, y)
    const float* __restrict__ dec_w,     // [E][64][128]
    const float* __restrict__ dec_b,     // [E][64]
    float* __restrict__ Q,               // [1024][64][4]  (zeroed)
    float* __restrict__ Bias,            // [1024][64]     (zeroed)
    float* __restrict__ Cnt)             // [1024]         (zeroed)
{
    const int p = blockIdx.x;
    const int tid = threadIdx.x;
    __shared__ float sL[512];
    sL[tid]       = latents[p * 512 + tid];
    sL[tid + 256] = latents[p * 512 + 256 + tid];
    __syncthreads();

    const int e = expert_ids[p];
    const int px = positions[p * 2 + 0];
    const int py = positions[p * 2 + 1];
    const int t = py * GRIDSZ + px;

    const int o = tid & 63;   // output channel
    const int k = tid >> 6;   // corner 0..3
    const float* wrow = dec_w + (e * OUTC + o) * CLAT;
    float q = 0.f;
#pragma unroll 8
    for (int c = 0; c < CLAT; ++c) q += wrow[c] * sL[c * 4 + k];
    atomicAdd(&Q[t * 256 + o * 4 + k], q);
    if (k == 0) atomicAdd(&Bias[t * 64 + o], dec_b[e * OUTC + o]);
    if (tid == 0) atomicAdd(&Cnt[t], 1.0f);
}

// ---------------------------------------------------------------------------
// Kernel 2: render fm rows [y0, y0+nrows) into a row-window buffer
// fm[64][R][512] (buffer row = y - y0). Pure closed-form bilinear of the
// per-tile corner sums -> recomputable per stripe at negligible cost.
// ---------------------------------------------------------------------------
__global__ __launch_bounds__(256) void render_rows(
    const float* __restrict__ Q, const float* __restrict__ Bias,
    const float* __restrict__ Cnt, float* __restrict__ fm,
    int y0, int nrows, int R)
{
    const int idx = blockIdx.x * 256 + threadIdx.x;
    if (idx >= nrows * IMG) return;
    const int row = idx >> 9;
    const int x = idx & 511;
    const int y = y0 + row;
    const int t = (y >> 4) * GRIDSZ + (x >> 4);
    const float ay = A16[y & 15];
    const float ax = A16[x & 15];
    const float inv = 1.0f / fmaxf(Cnt[t], 1.0f);
    const float* q = Q + t * 256;
    const float* bb = Bias + t * 64;
#pragma unroll 8
    for (int o = 0; o < OUTC; ++o) {
        const float q00 = q[o * 4 + 0], q01 = q[o * 4 + 1];
        const float q10 = q[o * 4 + 2], q11 = q[o * 4 + 3];
        float v = ay * (ax * q00 + (1.f - ax) * q01) +
                  (1.f - ay) * (ax * q10 + (1.f - ax) * q11);
        fm[(o * R + row) * IMG + x] = (v + bb[o]) * inv;
    }
}

// ---------------------------------------------------------------------------
// Kernel 3: direct 3x3 SAME conv on row-window buffers.
// in:  [CIN][Rin][512],  buffer row 0 = image row ybi
// out: [OC ][Rout][512], buffer row 0 = image row ybo
// Computes image rows [yo0, yo0+ny). Block = 64x4 pixels, OCT channels/thread.
// Weight indices are block-uniform -> scalar loads; fp32 vector-ALU FMAs
// (no fp32 MFMA on CDNA4).
// ---------------------------------------------------------------------------
template <int CIN, int OCT, bool RELU>
__global__ __launch_bounds__(256) void conv3x3_s(
    const float* __restrict__ in, int Rin, int ybi,
    const float* __restrict__ wgt, const float* __restrict__ bias,
    float* __restrict__ out, int Rout, int ybo, int yo0, int ny)
{
    const int tid = threadIdx.x;
    const int x = blockIdx.x * 64 + (tid & 63);
    const int yr = blockIdx.y * 4 + (tid >> 6);
    if (yr >= ny) return;
    const int y = yo0 + yr;
    const int oc0 = blockIdx.z * OCT;

    float acc[OCT];
#pragma unroll
    for (int o = 0; o < OCT; ++o) acc[o] = bias[oc0 + o];

    const bool vx0 = x > 0, vx2 = x < IMG - 1;
    const bool vy0 = y > 0, vy2 = y < IMG - 1;
    const float* pin = in + (size_t)(y - ybi) * IMG + x;  // row y, channel 0
    const float* pw = wgt + (size_t)oc0 * CIN * 9;

    for (int c = 0; c < CIN; ++c) {
        const float* pc = pin + (size_t)c * Rin * IMG;
        float v[9];
        v[0] = (vy0 && vx0) ? pc[-IMG - 1] : 0.f;
        v[1] = vy0 ? pc[-IMG] : 0.f;
        v[2] = (vy0 && vx2) ? pc[-IMG + 1] : 0.f;
        v[3] = vx0 ? pc[-1] : 0.f;
        v[4] = pc[0];
        v[5] = vx2 ? pc[1] : 0.f;
        v[6] = (vy2 && vx0) ? pc[IMG - 1] : 0.f;
        v[7] = vy2 ? pc[IMG] : 0.f;
        v[8] = (vy2 && vx2) ? pc[IMG + 1] : 0.f;
#pragma unroll
        for (int o = 0; o < OCT; ++o) {
            const float* wp = pw + (size_t)(o * CIN + c) * 9;
#pragma unroll
            for (int kk = 0; kk < 9; ++kk) acc[o] += wp[kk] * v[kk];
        }
    }

    float* pout = out + ((size_t)oc0 * Rout + (y - ybo)) * IMG + x;
#pragma unroll
    for (int o = 0; o < OCT; ++o) {
        float r = acc[o];
        if (RELU) r = fmaxf(r, 0.f);
        pout[(size_t)o * Rout * IMG] = r;
    }
}

// ---------------------------------------------------------------------------
extern "C" void kernel_launch(void* const* d_in, const int* in_sizes, int n_in,
                              void* d_out, int out_size, void* d_ws,
                              size_t ws_size, hipStream_t stream)
{
    const float* latents    = (const float*)d_in[0];
    const int*   expert_ids = (const int*)d_in[1];
    const int*   positions  = (const int*)d_in[2];
    const float* dec_w      = (const float*)d_in[3];
    const float* dec_b      = (const float*)d_in[4];
    const float* w1 = (const float*)d_in[5];
    const float* bw1 = (const float*)d_in[6];
    const float* w2 = (const float*)d_in[7];
    const float* bw2 = (const float*)d_in[8];
    const float* w3 = (const float*)d_in[9];
    const float* bw3 = (const float*)d_in[10];
    const float* w4 = (const float*)d_in[11];
    const float* bw4 = (const float*)d_in[12];
    float* out = (float*)d_out;
    char* ws = (char*)d_ws;

    // --- workspace layout, adaptive in ws_size (constant per process ->
    // identical launch sequence every call; graph-capture safe) -------------
    float *Q, *fmp, *h1p, *h2p, *h3p;
    int S, R0, R1, R2, R3;
    const size_t QBYTES = (size_t)(NPATCH * 256 + NPATCH * 64 + NPATCH) * 4;

    if (ws_size >= 384 * MiB) {
        // Full-image single stripe, buffers aliased by lifetime:
        //   region A @0      (256 MiB): fm (64 MiB) then h2 (256 MiB)
        //   region B @256MiB (128 MiB): Q, then h1, then h3
        S = 512; R0 = R1 = R2 = R3 = 512;
        fmp = (float*)ws;
        h2p = (float*)ws;
        h1p = (float*)(ws + 256 * MiB);
        h3p = h1p;
        Q   = h1p;           // Q dead once fm rendered; h1 written after
    } else {
        // Striped with halo recompute: pick largest stripe height that fits.
        // bytes(S) = QBYTES + (576*S + 2560) rows * 512 px * 4 B
        S = 4;
        const int cands[6] = {256, 128, 64, 32, 16, 8};
        for (int ci = 0; ci < 6; ++ci) {
            size_t need = QBYTES + (size_t)(576 * cands[ci] + 2560) * 2048;
            if (need <= ws_size) { S = cands[ci]; break; }
        }
        R0 = S + 8; R1 = S + 6; R2 = S + 4; R3 = S + 2;
        Q   = (float*)ws;
        fmp = (float*)(ws + QBYTES);
        h1p = fmp + (size_t)64 * R0 * IMG;
        h2p = h1p + (size_t)128 * R1 * IMG;
        h3p = h2p + (size_t)256 * R2 * IMG;
    }
    float* Bias = Q + NPATCH * 256;
    float* Cnt  = Bias + NPATCH * 64;

    // --- expert decode to per-tile corner sums -----------------------------
    const int NZ = NPATCH * 256 + NPATCH * 64 + NPATCH;
    zero_kernel<<<(NZ + 255) / 256, 256, 0, stream>>>(Q, NZ);
    patch_project<<<NPATCH, 256, 0, stream>>>(latents, expert_ids, positions,
                                              dec_w, dec_b, Q, Bias, Cnt);

    // --- conv head: 512/S stripes of {render, conv1..conv4} ----------------
    const int nstripes = IMG / S;
    for (int s = 0; s < nstripes; ++s) {
        const int r0 = s * S, r1 = r0 + S;
        const int lo3 = imax(r0 - 1, 0), hi3 = imin(r1 + 1, IMG);
        const int lo2 = imax(lo3 - 1, 0), hi2 = imin(hi3 + 1, IMG);
        const int lo1 = imax(lo2 - 1, 0), hi1 = imin(hi2 + 1, IMG);
        const int lo0 = imax(lo1 - 1, 0), hi0 = imin(hi1 + 1, IMG);

        const int n0 = hi0 - lo0;
        render_rows<<<(n0 * IMG + 255) / 256, 256, 0, stream>>>(
            Q, Bias, Cnt, fmp, lo0, n0, R0);

        conv3x3_s<64, 16, true>
            <<<dim3(8, (hi1 - lo1 + 3) / 4, 8), 256, 0, stream>>>(
                fmp, R0, lo0, w1, bw1, h1p, R1, lo1, lo1, hi1 - lo1);
        conv3x3_s<128, 16, true>
            <<<dim3(8, (hi2 - lo2 + 3) / 4, 16), 256, 0, stream>>>(
                h1p, R1, lo1, w2, bw2, h2p, R2, lo2, lo2, hi2 - lo2);
        conv3x3_s<256, 16, true>
            <<<dim3(8, (hi3 - lo3 + 3) / 4, 8), 256, 0, stream>>>(
                h2p, R2, lo2, w3, bw3, h3p, R3, lo3, lo3, hi3 - lo3);
        conv3x3_s<128, 3, false>
            <<<dim3(8, (S + 3) / 4, 1), 256, 0, stream>>>(
                h3p, R3, lo3, w4, bw4, out, IMG, 0, r0, S);
    }
}

// Round 8
// 1014.127 us; speedup vs baseline: 7.3809x; 7.3809x over previous
//
#include <hip/hip_runtime.h>

typedef _Float16 f16;
typedef _Float16 f16x8 __attribute__((ext_vector_type(8)));
typedef float f32x4 __attribute__((ext_vector_type(4)));

#define IMG 512
#define NPATCH 1024
#define GRIDSZ 32
#define CLAT 128
#define MiB (1048576UL)

static inline int imax(int a, int b) { return a > b ? a : b; }
static inline int imin(int a, int b) { return a < b ? a : b; }

// Composite 1D weight (corner-0 weight) for 2 -> 16 via three x2 bilinear
// (half-pixel centers, edge-clamped) upsamples. a[i] + a[15-i] == 1.
__device__ const float A16[16] = {
    1.0f, 0.984375f, 0.953125f, 0.90625f, 0.84375f, 0.765625f, 0.671875f,
    0.5625f, 0.4375f, 0.328125f, 0.234375f, 0.15625f, 0.09375f, 0.046875f,
    0.015625f, 0.0f};

// ---------------------------------------------------------------------------
__global__ __launch_bounds__(256) void zero_kernel(float* __restrict__ p, int n)
{
    int i = blockIdx.x * 256 + threadIdx.x;
    if (i < n) p[i] = 0.0f;
}

// ---------------------------------------------------------------------------
// Per-patch projection of the 4 latent corners through the expert's 1x1 conv,
// accumulated per tile (positions are tile-aligned; bilinear is linear).
// ---------------------------------------------------------------------------
__global__ __launch_bounds__(256) void patch_project(
    const float* __restrict__ latents, const int* __restrict__ expert_ids,
    const int* __restrict__ positions, const float* __restrict__ dec_w,
    const float* __restrict__ dec_b, float* __restrict__ Q,
    float* __restrict__ Bias, float* __restrict__ Cnt)
{
    const int p = blockIdx.x;
    const int tid = threadIdx.x;
    __shared__ float sL[512];
    sL[tid]       = latents[p * 512 + tid];
    sL[tid + 256] = latents[p * 512 + 256 + tid];
    __syncthreads();

    const int e = expert_ids[p];
    const int t = positions[p * 2 + 1] * GRIDSZ + positions[p * 2 + 0];
    const int o = tid & 63;
    const int k = tid >> 6;
    const float* wrow = dec_w + (e * 64 + o) * CLAT;
    float q = 0.f;
#pragma unroll 8
    for (int c = 0; c < CLAT; ++c) q += wrow[c] * sL[c * 4 + k];
    atomicAdd(&Q[t * 256 + o * 4 + k], q);
    if (k == 0) atomicAdd(&Bias[t * 64 + o], dec_b[e * 64 + o]);
    if (tid == 0) atomicAdd(&Cnt[t], 1.0f);
}

// ---------------------------------------------------------------------------
// Pack OIHW fp32 weights into fp16 MFMA B-tiles:
//   wt[tap][oc/16][c/32][ (oc%16)*32 + (c%32) ]  (each tile = 512 f16 = 1KiB)
// B-frag for lane l is then the 8 f16 at tile + (l%16)*32 + (l/16)*8.
// ---------------------------------------------------------------------------
__global__ __launch_bounds__(256) void wt_pack(const float* __restrict__ w,
                                               f16* __restrict__ wt,
                                               int OC, int CIN, int n)
{
    int idx = blockIdx.x * 256 + threadIdx.x;
    if (idx >= n) return;
    const int tap = idx % 9;
    const int c = (idx / 9) % CIN;
    const int oc = idx / (9 * CIN);
    const int tile = (tap * (OC >> 4) + (oc >> 4)) * (CIN >> 5) + (c >> 5);
    wt[tile * 512 + (oc & 15) * 32 + (c & 31)] = (f16)w[idx];
}

// ---------------------------------------------------------------------------
// Render fm rows [y0, y0+nrows) as fp16 NHWC [row][512][64].
// ---------------------------------------------------------------------------
__global__ __launch_bounds__(256) void render_rows(
    const float* __restrict__ Q, const float* __restrict__ Bias,
    const float* __restrict__ Cnt, f16* __restrict__ fm, int y0, int nrows)
{
    const int idx = blockIdx.x * 256 + threadIdx.x;
    if (idx >= nrows * IMG) return;
    const int row = idx >> 9, x = idx & 511;
    const int y = y0 + row;
    const int t = (y >> 4) * GRIDSZ + (x >> 4);
    const float ay = A16[y & 15], ax = A16[x & 15];
    const float inv = 1.0f / fmaxf(Cnt[t], 1.0f);
    const float* q = Q + t * 256;
    const float* bb = Bias + t * 64;
    f16* o = fm + ((size_t)row * IMG + x) * 64;
#pragma unroll
    for (int g = 0; g < 8; ++g) {
        f16x8 v8;
#pragma unroll
        for (int j = 0; j < 8; ++j) {
            const int oc = g * 8 + j;
            const float q00 = q[oc * 4 + 0], q01 = q[oc * 4 + 1];
            const float q10 = q[oc * 4 + 2], q11 = q[oc * 4 + 3];
            float v = ay * (ax * q00 + (1.f - ax) * q01) +
                      (1.f - ay) * (ax * q10 + (1.f - ax) * q11);
            v8[j] = (f16)((v + bb[oc]) * inv);
        }
        *(f16x8*)(o + g * 8) = v8;
    }
}

// ---------------------------------------------------------------------------
// MFMA implicit-GEMM 3x3 SAME conv, fp16 in/out (NHWC), fp32 accumulate, ReLU.
// WG = 256 thr = 4 waves; tile = 128 px (x-strip, one y) x 128 oc.
// Wave (wm,wn): 64 px x 64 oc via 4x4 frags of mfma_f32_16x16x32_f16.
//   D[m=px][n=oc] += A[px][c] * B[c][oc] per tap; K = c in chunks of 32.
// A staged in LDS: [3 rows][130 px][40 f16] (80B px-stride -> 2-per-bank reads).
// B read from packed wt tiles (1KiB coalesced bursts, L2-hot).
// ---------------------------------------------------------------------------
template <int CIN, int OC>
__global__ __launch_bounds__(256) void conv_mfma(
    const f16* __restrict__ in, int ybi,
    const f16* __restrict__ wt, const float* __restrict__ bias,
    f16* __restrict__ out, int ybo, int yo0)
{
    __shared__ f16 sIn[3 * 130 * 40];
    const int tid = threadIdx.x;
    const int lane = tid & 63;
    const int wv = tid >> 6;
    const int wm = wv & 1, wn = wv >> 1;
    const int l15 = lane & 15, l4 = lane >> 4;
    const int bx = blockIdx.x;
    const int y = yo0 + blockIdx.y;
    const int ocb = blockIdx.z * 128 + wn * 64;
    const int xleft = bx * 128 - 1;
    const int laneOffH = (l15 << 5) | (l4 << 3);

    f32x4 acc[4][4];
#pragma unroll
    for (int m = 0; m < 4; ++m)
#pragma unroll
        for (int n = 0; n < 4; ++n) acc[m][n] = (f32x4){0.f, 0.f, 0.f, 0.f};

    for (int c0 = 0; c0 < CIN; c0 += 32) {
        __syncthreads();
        // stage rows y-1..y+1, x in [xleft, xleft+130), c in [c0, c0+32)
        for (int g = tid; g < 1560; g += 256) {
            const int r = g / 520;
            const int rem = g - r * 520;
            const int px = rem >> 2;
            const int cg = rem & 3;
            const int gy = y - 1 + r;
            const int gx = xleft + px;
            f16x8 v;
#pragma unroll
            for (int j = 0; j < 8; ++j) v[j] = (f16)0.f;
            if (gy >= 0 && gy < IMG && gx >= 0 && gx < IMG)
                v = *(const f16x8*)(in +
                        ((size_t)(gy - ybi) * IMG + gx) * CIN + c0 + cg * 8);
            *(f16x8*)(&sIn[(r * 130 + px) * 40 + cg * 8]) = v;
        }
        __syncthreads();

        const int cT = c0 >> 5;
#pragma unroll
        for (int tap = 0; tap < 9; ++tap) {
            const int dy = tap / 3, dx = tap % 3;
            f16x8 afr[4], bfr[4];
#pragma unroll
            for (int m = 0; m < 4; ++m) {
                const int xl = wm * 64 + m * 16 + l15 + dx;
                afr[m] = *(const f16x8*)(&sIn[(dy * 130 + xl) * 40 + l4 * 8]);
            }
#pragma unroll
            for (int n = 0; n < 4; ++n) {
                const int tile =
                    (tap * (OC >> 4) + (ocb >> 4) + n) * (CIN >> 5) + cT;
                bfr[n] = *(const f16x8*)(wt + tile * 512 + laneOffH);
            }
#pragma unroll
            for (int m = 0; m < 4; ++m)
#pragma unroll
                for (int n = 0; n < 4; ++n)
                    acc[m][n] = __builtin_amdgcn_mfma_f32_16x16x32_f16(
                        afr[m], bfr[n], acc[m][n], 0, 0, 0);
        }
    }

    const int yb = y - ybo;
#pragma unroll
    for (int n = 0; n < 4; ++n) {
        const float bs = bias[ocb + n * 16 + l15];
#pragma unroll
        for (int m = 0; m < 4; ++m) {
            const int xo = bx * 128 + wm * 64 + m * 16 + l4 * 4;
            f16* po = out + ((size_t)yb * IMG + xo) * OC + ocb + n * 16 + l15;
#pragma unroll
            for (int r = 0; r < 4; ++r) {
                const float v = fmaxf(acc[m][n][r] + bs, 0.f);
                po[(size_t)r * OC] = (f16)v;
            }
        }
    }
}

// ---------------------------------------------------------------------------
// conv4: 128 -> 3, no ReLU. Scalar (3 oc won't pay for MFMA). Weights in LDS.
// Reads h3 fp16 NHWC; writes fp32 NCHW d_out.
// ---------------------------------------------------------------------------
__global__ __launch_bounds__(256) void conv4_k(
    const f16* __restrict__ in, int ybi, const float* __restrict__ w4,
    const float* __restrict__ b4, float* __restrict__ out, int yo0)
{
    __shared__ float sW[3456];
    const int tid = threadIdx.x;
    for (int i = tid; i < 3456; i += 256) sW[i] = w4[i];
    __syncthreads();
    const int idx = blockIdx.x * 256 + tid;
    const int x = idx & 511;
    const int y = yo0 + (idx >> 9);
    float a0 = b4[0], a1 = b4[1], a2 = b4[2];
#pragma unroll
    for (int tap = 0; tap < 9; ++tap) {
        const int gy = y + tap / 3 - 1, gx = x + tap % 3 - 1;
        if (gy < 0 || gy >= IMG || gx < 0 || gx >= IMG) continue;
        const f16* p = in + ((size_t)(gy - ybi) * IMG + gx) * 128;
#pragma unroll 4
        for (int cg = 0; cg < 16; ++cg) {
            const f16x8 v = *(const f16x8*)(p + cg * 8);
#pragma unroll
            for (int j = 0; j < 8; ++j) {
                const float vv = (float)v[j];
                const int c = cg * 8 + j;
                a0 += sW[c * 9 + tap] * vv;
                a1 += sW[(128 + c) * 9 + tap] * vv;
                a2 += sW[(256 + c) * 9 + tap] * vv;
            }
        }
    }
    out[y * IMG + x] = a0;
    out[262144 + y * IMG + x] = a1;
    out[524288 + y * IMG + x] = a2;
}

// ---------------------------------------------------------------------------
extern "C" void kernel_launch(void* const* d_in, const int* in_sizes, int n_in,
                              void* d_out, int out_size, void* d_ws,
                              size_t ws_size, hipStream_t stream)
{
    const float* latents    = (const float*)d_in[0];
    const int*   expert_ids = (const int*)d_in[1];
    const int*   positions  = (const int*)d_in[2];
    const float* dec_w      = (const float*)d_in[3];
    const float* dec_b      = (const float*)d_in[4];
    const float* w1 = (const float*)d_in[5];
    const float* bw1 = (const float*)d_in[6];
    const float* w2 = (const float*)d_in[7];
    const float* bw2 = (const float*)d_in[8];
    const float* w3 = (const float*)d_in[9];
    const float* bw3 = (const float*)d_in[10];
    const float* w4 = (const float*)d_in[11];
    const float* bw4 = (const float*)d_in[12];
    float* out = (float*)d_out;
    char* ws = (char*)d_ws;

    // ---- stripe height: largest S whose fp16 buffers fit ws ---------------
    // need(S) = Q(1,314,816) + WT(1,327,104) +
    //           (S+8)*64KB + (S+6)*128KB + (S+4)*256KB + (S+2)*128KB
    const int cands[7] = {512, 256, 128, 64, 32, 16, 8};
    int S = 8;
    for (int ci = 0; ci < 7; ++ci) {
        size_t need = 2641920UL + 4096UL + (size_t)(cands[ci] + 8) * 65536 +
                      (size_t)(cands[ci] + 6) * 131072 +
                      (size_t)(cands[ci] + 4) * 262144 +
                      (size_t)(cands[ci] + 2) * 131072;
        if (need <= ws_size) { S = cands[ci]; break; }
    }

    // ---- workspace layout (all offsets 256B-aligned) ----------------------
    size_t off = 0;
    float* Q    = (float*)(ws + off); off += (size_t)NPATCH * 256 * 4;
    float* Bias = (float*)(ws + off); off += (size_t)NPATCH * 64 * 4;
    float* Cnt  = (float*)(ws + off); off += (size_t)NPATCH * 4;
    f16* W1t = (f16*)(ws + off); off += (size_t)9 * 128 * 64 * 2;
    f16* W2t = (f16*)(ws + off); off += (size_t)9 * 256 * 128 * 2;
    f16* W3t = (f16*)(ws + off); off += (size_t)9 * 128 * 256 * 2;
    f16* fm = (f16*)(ws + off); off += (size_t)(S + 8) * IMG * 64 * 2;
    f16* h1 = (f16*)(ws + off); off += (size_t)(S + 6) * IMG * 128 * 2;
    f16* h2 = (f16*)(ws + off); off += (size_t)(S + 4) * IMG * 256 * 2;
    f16* h3 = (f16*)(ws + off);

    // ---- expert decode to per-tile corner sums ----------------------------
    const int NZ = NPATCH * 256 + NPATCH * 64 + NPATCH;
    zero_kernel<<<(NZ + 255) / 256, 256, 0, stream>>>(Q, NZ);
    patch_project<<<NPATCH, 256, 0, stream>>>(latents, expert_ids, positions,
                                              dec_w, dec_b, Q, Bias, Cnt);

    // ---- pack conv weights to fp16 MFMA tiles -----------------------------
    wt_pack<<<(73728 + 255) / 256, 256, 0, stream>>>(w1, W1t, 128, 64, 73728);
    wt_pack<<<(294912 + 255) / 256, 256, 0, stream>>>(w2, W2t, 256, 128, 294912);
    wt_pack<<<(294912 + 255) / 256, 256, 0, stream>>>(w3, W3t, 128, 256, 294912);

    // ---- conv head: 512/S stripes -----------------------------------------
    const int nstripes = IMG / S;
    for (int s = 0; s < nstripes; ++s) {
        const int r0 = s * S, r1 = r0 + S;
        const int lo3 = imax(r0 - 1, 0), hi3 = imin(r1 + 1, IMG);
        const int lo2 = imax(lo3 - 1, 0), hi2 = imin(hi3 + 1, IMG);
        const int lo1 = imax(lo2 - 1, 0), hi1 = imin(hi2 + 1, IMG);
        const int lo0 = imax(lo1 - 1, 0), hi0 = imin(hi1 + 1, IMG);

        const int n0 = hi0 - lo0;
        render_rows<<<n0 * 2, 256, 0, stream>>>(Q, Bias, Cnt, fm, lo0, n0);

        conv_mfma<64, 128><<<dim3(4, hi1 - lo1, 1), 256, 0, stream>>>(
            fm, lo0, W1t, bw1, h1, lo1, lo1);
        conv_mfma<128, 256><<<dim3(4, hi2 - lo2, 2), 256, 0, stream>>>(
            h1, lo1, W2t, bw2, h2, lo2, lo2);
        conv_mfma<256, 128><<<dim3(4, hi3 - lo3, 1), 256, 0, stream>>>(
            h2, lo2, W3t, bw3, h3, lo3, lo3);
        conv4_k<<<S * 2, 256, 0, stream>>>(h3, lo3, w4, bw4, out, r0);
    }
}

// Round 10
// 730.890 us; speedup vs baseline: 10.2412x; 1.3875x over previous
//
#include <hip/hip_runtime.h>

typedef _Float16 f16;
typedef _Float16 f16x8 __attribute__((ext_vector_type(8)));
typedef float f32x4 __attribute__((ext_vector_type(4)));

#define IMG 512
#define NPATCH 1024
#define GRIDSZ 32
#define CLAT 128
#define MiB (1048576UL)

static inline int imax(int a, int b) { return a > b ? a : b; }
static inline int imin(int a, int b) { return a < b ? a : b; }

// Composite 1D weight (corner-0 weight) for 2 -> 16 via three x2 bilinear
// (half-pixel centers, edge-clamped) upsamples. a[i] + a[15-i] == 1.
__device__ const float A16[16] = {
    1.0f, 0.984375f, 0.953125f, 0.90625f, 0.84375f, 0.765625f, 0.671875f,
    0.5625f, 0.4375f, 0.328125f, 0.234375f, 0.15625f, 0.09375f, 0.046875f,
    0.015625f, 0.0f};

// ---------------------------------------------------------------------------
__global__ __launch_bounds__(256) void zero_kernel(float* __restrict__ p, int n)
{
    int i = blockIdx.x * 256 + threadIdx.x;
    if (i < n) p[i] = 0.0f;
}

// ---------------------------------------------------------------------------
// Per-patch projection of the 4 latent corners through the expert's 1x1 conv,
// accumulated per tile (positions are tile-aligned; bilinear is linear).
// ---------------------------------------------------------------------------
__global__ __launch_bounds__(256) void patch_project(
    const float* __restrict__ latents, const int* __restrict__ expert_ids,
    const int* __restrict__ positions, const float* __restrict__ dec_w,
    const float* __restrict__ dec_b, float* __restrict__ Q,
    float* __restrict__ Bias, float* __restrict__ Cnt)
{
    const int p = blockIdx.x;
    const int tid = threadIdx.x;
    __shared__ float sL[512];
    sL[tid]       = latents[p * 512 + tid];
    sL[tid + 256] = latents[p * 512 + 256 + tid];
    __syncthreads();

    const int e = expert_ids[p];
    const int t = positions[p * 2 + 1] * GRIDSZ + positions[p * 2 + 0];
    const int o = tid & 63;
    const int k = tid >> 6;
    const float* wrow = dec_w + (e * 64 + o) * CLAT;
    float q = 0.f;
#pragma unroll 8
    for (int c = 0; c < CLAT; ++c) q += wrow[c] * sL[c * 4 + k];
    atomicAdd(&Q[t * 256 + o * 4 + k], q);
    if (k == 0) atomicAdd(&Bias[t * 64 + o], dec_b[e * 64 + o]);
    if (tid == 0) atomicAdd(&Cnt[t], 1.0f);
}

// ---------------------------------------------------------------------------
// Pack OIHW fp32 weights into fp16 MFMA B-tiles:
//   wt[tap][oc/16][c/32][ (oc%16)*32 + (c%32) ]  (each tile = 512 f16 = 1KiB)
// B-frag for lane l: 8 f16 at tile + (l%16)*32 + (l/16)*8.
// For conv4, OC is padded to 16 (tiles pre-zeroed; only oc<3 written).
// ---------------------------------------------------------------------------
__global__ __launch_bounds__(256) void wt_pack(const float* __restrict__ w,
                                               f16* __restrict__ wt,
                                               int OC, int CIN, int n)
{
    int idx = blockIdx.x * 256 + threadIdx.x;
    if (idx >= n) return;
    const int tap = idx % 9;
    const int c = (idx / 9) % CIN;
    const int oc = idx / (9 * CIN);
    const int tile = (tap * (OC >> 4) + (oc >> 4)) * (CIN >> 5) + (c >> 5);
    wt[tile * 512 + (oc & 15) * 32 + (c & 31)] = (f16)w[idx];
}

// ---------------------------------------------------------------------------
// Render fm rows [y0, y0+nrows) as fp16 NHWC [row][512][64].
// ---------------------------------------------------------------------------
__global__ __launch_bounds__(256) void render_rows(
    const float* __restrict__ Q, const float* __restrict__ Bias,
    const float* __restrict__ Cnt, f16* __restrict__ fm, int y0, int nrows)
{
    const int idx = blockIdx.x * 256 + threadIdx.x;
    if (idx >= nrows * IMG) return;
    const int row = idx >> 9, x = idx & 511;
    const int y = y0 + row;
    const int t = (y >> 4) * GRIDSZ + (x >> 4);
    const float ay = A16[y & 15], ax = A16[x & 15];
    const float inv = 1.0f / fmaxf(Cnt[t], 1.0f);
    const float* q = Q + t * 256;
    const float* bb = Bias + t * 64;
    f16* o = fm + ((size_t)row * IMG + x) * 64;
#pragma unroll
    for (int g = 0; g < 8; ++g) {
        f16x8 v8;
#pragma unroll
        for (int j = 0; j < 8; ++j) {
            const int oc = g * 8 + j;
            const float q00 = q[oc * 4 + 0], q01 = q[oc * 4 + 1];
            const float q10 = q[oc * 4 + 2], q11 = q[oc * 4 + 3];
            float v = ay * (ax * q00 + (1.f - ax) * q01) +
                      (1.f - ay) * (ax * q10 + (1.f - ax) * q11);
            v8[j] = (f16)((v + bb[oc]) * inv);
        }
        *(f16x8*)(o + g * 8) = v8;
    }
}

// ---------------------------------------------------------------------------
// MFMA implicit-GEMM 3x3 SAME conv, fp16 NHWC, fp32 accumulate, ReLU.
// WG = 4 waves; tile = 128 px x 128 oc; wave = 64 px x 64 oc, 4x4 frags of
// mfma_f32_16x16x32_f16. Staging slots (addresses chunk-invariant) are
// precomputed once; chunk c+1's global loads issue before chunk c's MFMA
// phase (register double-buffer) so HBM/L2 latency hides under compute.
// ---------------------------------------------------------------------------
template <int CIN, int OC>
__global__ __launch_bounds__(256) void conv_mfma(
    const f16* __restrict__ in, int ybi,
    const f16* __restrict__ wt, const float* __restrict__ bias,
    f16* __restrict__ out, int ybo, int yo0)
{
    __shared__ f16 sIn[3 * 130 * 40];
    const int tid = threadIdx.x;
    const int lane = tid & 63;
    const int wv = tid >> 6;
    const int wm = wv & 1, wn = wv >> 1;
    const int l15 = lane & 15, l4 = lane >> 4;
    const int bx = blockIdx.x;
    const int y = yo0 + blockIdx.y;
    const int ocb = blockIdx.z * 128 + wn * 64;
    const int xleft = bx * 128 - 1;
    const int laneOffH = (l15 << 5) | (l4 << 3);

    // per-thread staging slots: 7 = ceil(1560/256); addresses chunk-invariant
    bool act[7], gok[7];
    const f16* gp[7];
    int lo[7];
#pragma unroll
    for (int i = 0; i < 7; ++i) {
        const int g = tid + i * 256;
        act[i] = g < 1560;
        const int r = g / 520;
        const int rem = g - r * 520;
        const int px = rem >> 2, cg = rem & 3;
        const int gy = y - 1 + r, gx = xleft + px;
        gok[i] = act[i] && gy >= 0 && gy < IMG && gx >= 0 && gx < IMG;
        gp[i] = in + ((size_t)(gy - ybi) * IMG + gx) * CIN + cg * 8;
        lo[i] = (r * 130 + px) * 40 + cg * 8;
    }

    f32x4 acc[4][4];
#pragma unroll
    for (int m = 0; m < 4; ++m)
#pragma unroll
        for (int n = 0; n < 4; ++n) acc[m][n] = (f32x4){0.f, 0.f, 0.f, 0.f};

    f16x8 vreg[7];
#pragma unroll
    for (int i = 0; i < 7; ++i) {
        f16x8 z;
#pragma unroll
        for (int j = 0; j < 8; ++j) z[j] = (f16)0.f;
        vreg[i] = gok[i] ? *(const f16x8*)(gp[i]) : z;
    }

    for (int c0 = 0; c0 < CIN; c0 += 32) {
        __syncthreads();
#pragma unroll
        for (int i = 0; i < 7; ++i)
            if (act[i]) *(f16x8*)(&sIn[lo[i]]) = vreg[i];
        __syncthreads();
        if (c0 + 32 < CIN) {
#pragma unroll
            for (int i = 0; i < 7; ++i) {
                f16x8 z;
#pragma unroll
                for (int j = 0; j < 8; ++j) z[j] = (f16)0.f;
                vreg[i] = gok[i] ? *(const f16x8*)(gp[i] + c0 + 32) : z;
            }
        }

        const int cT = c0 >> 5;
#pragma unroll
        for (int tap = 0; tap < 9; ++tap) {
            const int dy = tap / 3, dx = tap % 3;
            f16x8 afr[4], bfr[4];
#pragma unroll
            for (int m = 0; m < 4; ++m) {
                const int xl = wm * 64 + m * 16 + l15 + dx;
                afr[m] = *(const f16x8*)(&sIn[(dy * 130 + xl) * 40 + l4 * 8]);
            }
#pragma unroll
            for (int n = 0; n < 4; ++n) {
                const int tile =
                    (tap * (OC >> 4) + (ocb >> 4) + n) * (CIN >> 5) + cT;
                bfr[n] = *(const f16x8*)(wt + tile * 512 + laneOffH);
            }
#pragma unroll
            for (int m = 0; m < 4; ++m)
#pragma unroll
                for (int n = 0; n < 4; ++n)
                    acc[m][n] = __builtin_amdgcn_mfma_f32_16x16x32_f16(
                        afr[m], bfr[n], acc[m][n], 0, 0, 0);
        }
    }

    const int yb = y - ybo;
#pragma unroll
    for (int n = 0; n < 4; ++n) {
        const float bs = bias[ocb + n * 16 + l15];
#pragma unroll
        for (int m = 0; m < 4; ++m) {
            const int xo = bx * 128 + wm * 64 + m * 16 + l4 * 4;
            f16* po = out + ((size_t)yb * IMG + xo) * OC + ocb + n * 16 + l15;
#pragma unroll
            for (int r = 0; r < 4; ++r) {
                const float v = fmaxf(acc[m][n][r] + bs, 0.f);
                po[(size_t)r * OC] = (f16)v;
            }
        }
    }
}

// ---------------------------------------------------------------------------
// conv4 as MFMA: 128 -> 16 oc (3 real, tiles pre-zeroed), no ReLU.
// Same staged implicit-GEMM; wave = 32 px x 16 oc (m=2, n=1).
// Writes fp32 NCHW d_out for oc<3.
// ---------------------------------------------------------------------------
__global__ __launch_bounds__(256) void conv4_mfma(
    const f16* __restrict__ in, int ybi, const f16* __restrict__ wt,
    const float* __restrict__ b4, float* __restrict__ out, int yo0)
{
    __shared__ f16 sIn[3 * 130 * 40];
    const int tid = threadIdx.x;
    const int lane = tid & 63;
    const int wv = tid >> 6;
    const int l15 = lane & 15, l4 = lane >> 4;
    const int bx = blockIdx.x;
    const int y = yo0 + blockIdx.y;
    const int xleft = bx * 128 - 1;
    const int laneOffH = (l15 << 5) | (l4 << 3);

    bool act[7], gok[7];
    const f16* gp[7];
    int lo[7];
#pragma unroll
    for (int i = 0; i < 7; ++i) {
        const int g = tid + i * 256;
        act[i] = g < 1560;
        const int r = g / 520;
        const int rem = g - r * 520;
        const int px = rem >> 2, cg = rem & 3;
        const int gy = y - 1 + r, gx = xleft + px;
        gok[i] = act[i] && gy >= 0 && gy < IMG && gx >= 0 && gx < IMG;
        gp[i] = in + ((size_t)(gy - ybi) * IMG + gx) * 128 + cg * 8;
        lo[i] = (r * 130 + px) * 40 + cg * 8;
    }

    f32x4 acc[2];
    acc[0] = (f32x4){0.f, 0.f, 0.f, 0.f};
    acc[1] = (f32x4){0.f, 0.f, 0.f, 0.f};

    f16x8 vreg[7];
#pragma unroll
    for (int i = 0; i < 7; ++i) {
        f16x8 z;
#pragma unroll
        for (int j = 0; j < 8; ++j) z[j] = (f16)0.f;
        vreg[i] = gok[i] ? *(const f16x8*)(gp[i]) : z;
    }

    for (int c0 = 0; c0 < 128; c0 += 32) {
        __syncthreads();
#pragma unroll
        for (int i = 0; i < 7; ++i)
            if (act[i]) *(f16x8*)(&sIn[lo[i]]) = vreg[i];
        __syncthreads();
        if (c0 + 32 < 128) {
#pragma unroll
            for (int i = 0; i < 7; ++i) {
                f16x8 z;
#pragma unroll
                for (int j = 0; j < 8; ++j) z[j] = (f16)0.f;
                vreg[i] = gok[i] ? *(const f16x8*)(gp[i] + c0 + 32) : z;
            }
        }

        const int cT = c0 >> 5;
#pragma unroll
        for (int tap = 0; tap < 9; ++tap) {
            const int dy = tap / 3, dx = tap % 3;
            const f16x8 bfr = *(const f16x8*)(wt + (tap * 4 + cT) * 512 +
                                              laneOffH);
#pragma unroll
            for (int m = 0; m < 2; ++m) {
                const int xl = wv * 32 + m * 16 + l15 + dx;
                const f16x8 afr =
                    *(const f16x8*)(&sIn[(dy * 130 + xl) * 40 + l4 * 8]);
                acc[m] = __builtin_amdgcn_mfma_f32_16x16x32_f16(
                    afr, bfr, acc[m], 0, 0, 0);
            }
        }
    }

    const int oc = l15;
    if (oc < 3) {
        const float bs = b4[oc];
#pragma unroll
        for (int m = 0; m < 2; ++m) {
            const int x = bx * 128 + wv * 32 + m * 16 + l4 * 4;
            float* po = out + oc * 262144 + y * IMG + x;
#pragma unroll
            for (int r = 0; r < 4; ++r) po[r] = acc[m][r] + bs;
        }
    }
}

// ---------------------------------------------------------------------------
extern "C" void kernel_launch(void* const* d_in, const int* in_sizes, int n_in,
                              void* d_out, int out_size, void* d_ws,
                              size_t ws_size, hipStream_t stream)
{
    const float* latents    = (const float*)d_in[0];
    const int*   expert_ids = (const int*)d_in[1];
    const int*   positions  = (const int*)d_in[2];
    const float* dec_w      = (const float*)d_in[3];
    const float* dec_b      = (const float*)d_in[4];
    const float* w1 = (const float*)d_in[5];
    const float* bw1 = (const float*)d_in[6];
    const float* w2 = (const float*)d_in[7];
    const float* bw2 = (const float*)d_in[8];
    const float* w3 = (const float*)d_in[9];
    const float* bw3 = (const float*)d_in[10];
    const float* w4 = (const float*)d_in[11];
    const float* bw4 = (const float*)d_in[12];
    float* out = (float*)d_out;
    char* ws = (char*)d_ws;

    // ---- stripe height: largest S whose fp16 buffers fit ws ---------------
    // fixed = Q/Bias/Cnt (1,314,816) + W4t (73,728) + W1t..W3t (1,327,104)
    const size_t FIXED = 2715648UL;
    const int cands[7] = {512, 256, 128, 64, 32, 16, 8};
    int S = 8;
    for (int ci = 0; ci < 7; ++ci) {
        size_t need = FIXED + (size_t)(cands[ci] + 8) * 65536 +
                      (size_t)(cands[ci] + 6) * 131072 +
                      (size_t)(cands[ci] + 4) * 262144 +
                      (size_t)(cands[ci] + 2) * 131072;
        if (need <= ws_size) { S = cands[ci]; break; }
    }

    // ---- workspace layout (all region sizes multiples of 256 B) -----------
    size_t off = 0;
    float* Q    = (float*)(ws + off); off += (size_t)NPATCH * 256 * 4;
    float* Bias = (float*)(ws + off); off += (size_t)NPATCH * 64 * 4;
    float* Cnt  = (float*)(ws + off); off += (size_t)NPATCH * 4;
    f16* W4t = (f16*)(ws + off); off += (size_t)9 * 16 * 128 * 4;  // zeroed
    f16* W1t = (f16*)(ws + off); off += (size_t)9 * 128 * 64 * 2;
    f16* W2t = (f16*)(ws + off); off += (size_t)9 * 256 * 128 * 2;
    f16* W3t = (f16*)(ws + off); off += (size_t)9 * 128 * 256 * 2;
    f16* fm = (f16*)(ws + off); off += (size_t)(S + 8) * IMG * 64 * 2;
    f16* h1 = (f16*)(ws + off); off += (size_t)(S + 6) * IMG * 128 * 2;
    f16* h2 = (f16*)(ws + off); off += (size_t)(S + 4) * IMG * 256 * 2;
    f16* h3 = (f16*)(ws + off);

    // ---- zero Q/Bias/Cnt + W4t (contiguous), then decode ------------------
    const int NZ = NPATCH * 256 + NPATCH * 64 + NPATCH + 18432;
    zero_kernel<<<(NZ + 255) / 256, 256, 0, stream>>>(Q, NZ);
    patch_project<<<NPATCH, 256, 0, stream>>>(latents, expert_ids, positions,
                                              dec_w, dec_b, Q, Bias, Cnt);

    // ---- pack conv weights to fp16 MFMA tiles -----------------------------
    wt_pack<<<(73728 + 255) / 256, 256, 0, stream>>>(w1, W1t, 128, 64, 73728);
    wt_pack<<<(294912 + 255) / 256, 256, 0, stream>>>(w2, W2t, 256, 128, 294912);
    wt_pack<<<(294912 + 255) / 256, 256, 0, stream>>>(w3, W3t, 128, 256, 294912);
    wt_pack<<<(3456 + 255) / 256, 256, 0, stream>>>(w4, W4t, 16, 128, 3456);

    // ---- conv head: 512/S stripes -----------------------------------------
    const int nstripes = IMG / S;
    for (int s = 0; s < nstripes; ++s) {
        const int r0 = s * S, r1 = r0 + S;
        const int lo3 = imax(r0 - 1, 0), hi3 = imin(r1 + 1, IMG);
        const int lo2 = imax(lo3 - 1, 0), hi2 = imin(hi3 + 1, IMG);
        const int lo1 = imax(lo2 - 1, 0), hi1 = imin(hi2 + 1, IMG);
        const int lo0 = imax(lo1 - 1, 0), hi0 = imin(hi1 + 1, IMG);

        const int n0 = hi0 - lo0;
        render_rows<<<n0 * 2, 256, 0, stream>>>(Q, Bias, Cnt, fm, lo0, n0);

        conv_mfma<64, 128><<<dim3(4, hi1 - lo1, 1), 256, 0, stream>>>(
            fm, lo0, W1t, bw1, h1, lo1, lo1);
        conv_mfma<128, 256><<<dim3(4, hi2 - lo2, 2), 256, 0, stream>>>(
            h1, lo1, W2t, bw2, h2, lo2, lo2);
        conv_mfma<256, 128><<<dim3(4, hi3 - lo3, 1), 256, 0, stream>>>(
            h2, lo2, W3t, bw3, h3, lo3, lo3);
        conv4_mfma<<<dim3(4, S), 256, 0, stream>>>(h3, lo3, W4t, bw4, out, r0);
    }
}